// Round 2
// baseline (349.316 us; speedup 1.0000x reference)
//
#include <hip/hip_runtime.h>

#define TINY 1e-6f

constexpr int N_PIX = 256 * 512;   // 131072 pixels, S = 64 samples

// 12-byte sample: loads merge to global_load_dwordx3 (4B-aligned, contiguous).
struct f3 { float x, y, z; };

__device__ __forceinline__ float clamp01(float x) {
    return fminf(fmaxf(x, 0.0f), 1.0f);
}

__device__ __forceinline__ float frcp(float x) {
    return __builtin_amdgcn_rcpf(x);
}

// 16 lanes per pixel, 4 samples per lane, ONE WHOLE SAMPLE (12 B) per load.
// Load k (k=0..3): lane sub reads sample 16k+sub at byte off k*192 + sub*12
// within its pixel's 768 B span. Consecutive lanes are byte-contiguous, so a
// wave64 instruction touches 4 x 192 B = 12 FULL cache lines (no partial
// lines), vs 48 partially-consumed lines for the previous 48 B-stride dwordx4
// scheme. Same bytes, 3x fewer L1/TA line-probes.
__global__ void __launch_bounds__(256)
shade_kernel(const float* __restrict__ normal,
             const float* __restrict__ albedo,
             const float* __restrict__ roughness,
             const float* __restrict__ points,
             const float* __restrict__ cam,
             const float* __restrict__ ldir,
             const float* __restrict__ dlight,
             const float* __restrict__ hdir,
             const float* __restrict__ slight,
             float* __restrict__ out)
{
    const int tid = blockIdx.x * 256 + threadIdx.x;
    const int pix = tid >> 4;          // one pixel per 16-lane group
    const int sub = tid & 15;          // lane-in-group

    // ---- issue all 16 sample loads up front (independent, coalesced) ----
    const size_t pbase = (size_t)pix * 192;   // floats per pixel per array
    const int    loff  = sub * 3;             // sample `sub` within 16-block

    f3 Lv[4], Dv[4], Hv[4], Sv[4];
#pragma unroll
    for (int k = 0; k < 4; ++k) {
        const size_t o = pbase + (size_t)(k * 48 + loff);  // sample 16k+sub
        Lv[k] = *(const f3*)(ldir   + o);
        Dv[k] = *(const f3*)(dlight + o);
        Hv[k] = *(const f3*)(hdir   + o);
        Sv[k] = *(const f3*)(slight + o);
    }

    // ---- per-pixel constants (small arrays, L2/L3-resident) ----
    const float nx = normal[pix * 3 + 0];
    const float ny = normal[pix * 3 + 1];
    const float nz = normal[pix * 3 + 2];
    const float r  = roughness[pix];
    const float px = points[pix * 3 + 0];
    const float py = points[pix * 3 + 1];
    const float pz = points[pix * 3 + 2];
    const float cx = cam[0], cy = cam[1], cz = cam[2];

    const float dx = cx - px, dy = cy - py, dz = cz - pz;
    const float len = sqrtf(dx * dx + dy * dy + dz * dz);
    const float inv = frcp(fmaxf(len, 1e-4f));
    const float vx = dx * inv, vy = dy * inv, vz = dz * inv;

    const float ndv = clamp01(nx * vx + ny * vy + nz * vz);
    const float k1  = (r + 1.0f) * (r + 1.0f) * 0.125f;
    const float omk = 1.0f - k1;
    const float g1v = ndv * frcp(fmaxf(ndv * omk + k1, TINY));

    float dacc0 = 0.f, dacc1 = 0.f, dacc2 = 0.f;
    float sacc0 = 0.f, sacc1 = 0.f, sacc2 = 0.f;

#pragma unroll
    for (int j = 0; j < 4; ++j) {
        const float lx = Lv[j].x, ly = Lv[j].y, lz = Lv[j].z;
        const float d0 = Dv[j].x, d1 = Dv[j].y, d2 = Dv[j].z;
        const float hx = Hv[j].x, hy = Hv[j].y, hz = Hv[j].z;
        const float s0 = Sv[j].x, s1 = Sv[j].y, s2 = Sv[j].z;

        const float ndl_d = clamp01(nx * lx + ny * ly + nz * lz);
        dacc0 += d0 * ndl_d;
        dacc1 += d1 * ndl_d;
        dacc2 += d2 * ndl_d;

        const float vdh = clamp01(hx * vx + hy * vy + hz * vz);
        const float tv  = 2.0f * vdh;
        const float lsx = tv * hx - vx;
        const float lsy = tv * hy - vy;
        const float lsz = tv * hz - vz;
        const float ndl = clamp01(nx * lsx + ny * lsy + nz * lsz);
        const float ndh = clamp01(nx * hx + ny * hy + nz * hz);
        const float f   = 0.04f + 0.96f * exp2f((-5.55472f * vdh - 6.98316f) * vdh);
        const float g1l = ndl * frcp(fmaxf(ndl * omk + k1, TINY));
        const float brdf = f * g1l * g1v * frcp(fmaxf(4.0f * ndl * ndv, TINY));
        const float wgt  = brdf * ndl * 4.0f * vdh * frcp(fmaxf(ndh, TINY));
        sacc0 += s0 * wgt;
        sacc1 += s1 * wgt;
        sacc2 += s2 * wgt;
    }

    // ---- butterfly reduction within each 16-lane group ----
#pragma unroll
    for (int off = 1; off < 16; off <<= 1) {
        dacc0 += __shfl_xor(dacc0, off);
        dacc1 += __shfl_xor(dacc1, off);
        dacc2 += __shfl_xor(dacc2, off);
        sacc0 += __shfl_xor(sacc0, off);
        sacc1 += __shfl_xor(sacc1, off);
        sacc2 += __shfl_xor(sacc2, off);
    }

    if (sub == 0) {
        const float ax = albedo[pix * 3 + 0];
        const float ay = albedo[pix * 3 + 1];
        const float az = albedo[pix * 3 + 2];
        const float inv_s = 1.0f / 64.0f;
        out[pix * 3 + 0] = (dacc0 * ax * 2.0f + sacc0) * inv_s;
        out[pix * 3 + 1] = (dacc1 * ay * 2.0f + sacc1) * inv_s;
        out[pix * 3 + 2] = (dacc2 * az * 2.0f + sacc2) * inv_s;
    }
}

extern "C" void kernel_launch(void* const* d_in, const int* in_sizes, int n_in,
                              void* d_out, int out_size, void* d_ws, size_t ws_size,
                              hipStream_t stream) {
    const float* normal    = (const float*)d_in[0];
    const float* albedo    = (const float*)d_in[1];
    const float* roughness = (const float*)d_in[2];
    const float* points    = (const float*)d_in[3];
    const float* cam       = (const float*)d_in[4];
    const float* ldir      = (const float*)d_in[5];
    const float* dlight    = (const float*)d_in[6];
    const float* hdir      = (const float*)d_in[7];
    const float* slight    = (const float*)d_in[8];
    float* out = (float*)d_out;

    // 16 lanes per pixel -> 16 pixels per 256-thread block
    const int blocks = N_PIX / 16;  // 8192
    shade_kernel<<<blocks, 256, 0, stream>>>(normal, albedo, roughness, points,
                                             cam, ldir, dlight, hdir, slight, out);
}

// Round 4
// 349.204 us; speedup vs baseline: 1.0003x; 1.0003x over previous
//
#include <hip/hip_runtime.h>

#define TINY 1e-6f

constexpr int N_PIX = 256 * 512;   // 131072 pixels, S = 64 samples

// 12-byte sample: loads merge to global_load_dwordx3 (4B-aligned, contiguous).
struct f3 { float x, y, z; };

__device__ __forceinline__ float clamp01(float x) {
    return fminf(fmaxf(x, 0.0f), 1.0f);
}

__device__ __forceinline__ float frcp(float x) {
    return __builtin_amdgcn_rcpf(x);
}

// 16 lanes per pixel, 4 samples per lane, one whole sample (12 B) per load.
// Load k (k=0..3): lane sub reads sample 16k+sub. Consecutive lanes are
// byte-contiguous -> each wave64 instruction covers 12 FULL cache lines.
//
// __launch_bounds__(256, 2): min 2 waves/EU -> VGPR cap 256. The previous
// single-arg launch_bounds let the backend target 8 waves/EU, capping the
// allocator at 32 VGPRs -- too few to hold the 16-load batch (48 payload
// VGPRs), so the compiler serialized the loads into a latency chain
// (confirmed: L3-warm dispatches with FETCH~0 ran at the same 128 us as
// HBM-cold ones => latency-bound, not BW-bound). With the cap relaxed, all
// 16 loads stay in flight per wave; even 8 waves/CU gives 96 KB in flight
// per CU, far above the ~15 KB Little's-law requirement for 6.3 TB/s.
__global__ void __launch_bounds__(256, 2)
shade_kernel(const float* __restrict__ normal,
             const float* __restrict__ albedo,
             const float* __restrict__ roughness,
             const float* __restrict__ points,
             const float* __restrict__ cam,
             const float* __restrict__ ldir,
             const float* __restrict__ dlight,
             const float* __restrict__ hdir,
             const float* __restrict__ slight,
             float* __restrict__ out)
{
    const int tid = blockIdx.x * 256 + threadIdx.x;
    const int pix = tid >> 4;          // one pixel per 16-lane group
    const int sub = tid & 15;          // lane-in-group

    // ---- issue all 16 sample loads up front (independent, coalesced) ----
    const size_t pbase = (size_t)pix * 192;   // floats per pixel per array
    const int    loff  = sub * 3;             // sample `sub` within 16-block

    f3 Lv[4], Dv[4], Hv[4], Sv[4];
#pragma unroll
    for (int k = 0; k < 4; ++k) {
        const size_t o = pbase + (size_t)(k * 48 + loff);  // sample 16k+sub
        Lv[k] = *(const f3*)(ldir   + o);
        Dv[k] = *(const f3*)(dlight + o);
        Hv[k] = *(const f3*)(hdir   + o);
        Sv[k] = *(const f3*)(slight + o);
    }

    // ---- per-pixel constants (small arrays, L2/L3-resident) ----
    const float nx = normal[pix * 3 + 0];
    const float ny = normal[pix * 3 + 1];
    const float nz = normal[pix * 3 + 2];
    const float r  = roughness[pix];
    const float px = points[pix * 3 + 0];
    const float py = points[pix * 3 + 1];
    const float pz = points[pix * 3 + 2];
    const float cx = cam[0], cy = cam[1], cz = cam[2];

    const float dx = cx - px, dy = cy - py, dz = cz - pz;
    const float len = sqrtf(dx * dx + dy * dy + dz * dz);
    const float inv = frcp(fmaxf(len, 1e-4f));
    const float vx = dx * inv, vy = dy * inv, vz = dz * inv;

    const float ndv = clamp01(nx * vx + ny * vy + nz * vz);
    const float k1  = (r + 1.0f) * (r + 1.0f) * 0.125f;
    const float omk = 1.0f - k1;
    const float g1v = ndv * frcp(fmaxf(ndv * omk + k1, TINY));

    float dacc0 = 0.f, dacc1 = 0.f, dacc2 = 0.f;
    float sacc0 = 0.f, sacc1 = 0.f, sacc2 = 0.f;

#pragma unroll
    for (int j = 0; j < 4; ++j) {
        const float lx = Lv[j].x, ly = Lv[j].y, lz = Lv[j].z;
        const float d0 = Dv[j].x, d1 = Dv[j].y, d2 = Dv[j].z;
        const float hx = Hv[j].x, hy = Hv[j].y, hz = Hv[j].z;
        const float s0 = Sv[j].x, s1 = Sv[j].y, s2 = Sv[j].z;

        const float ndl_d = clamp01(nx * lx + ny * ly + nz * lz);
        dacc0 += d0 * ndl_d;
        dacc1 += d1 * ndl_d;
        dacc2 += d2 * ndl_d;

        const float vdh = clamp01(hx * vx + hy * vy + hz * vz);
        const float tv  = 2.0f * vdh;
        const float lsx = tv * hx - vx;
        const float lsy = tv * hy - vy;
        const float lsz = tv * hz - vz;
        const float ndl = clamp01(nx * lsx + ny * lsy + nz * lsz);
        const float ndh = clamp01(nx * hx + ny * hy + nz * hz);
        const float f   = 0.04f + 0.96f * exp2f((-5.55472f * vdh - 6.98316f) * vdh);
        const float g1l = ndl * frcp(fmaxf(ndl * omk + k1, TINY));
        const float brdf = f * g1l * g1v * frcp(fmaxf(4.0f * ndl * ndv, TINY));
        const float wgt  = brdf * ndl * 4.0f * vdh * frcp(fmaxf(ndh, TINY));
        sacc0 += s0 * wgt;
        sacc1 += s1 * wgt;
        sacc2 += s2 * wgt;
    }

    // ---- butterfly reduction within each 16-lane group ----
#pragma unroll
    for (int off = 1; off < 16; off <<= 1) {
        dacc0 += __shfl_xor(dacc0, off);
        dacc1 += __shfl_xor(dacc1, off);
        dacc2 += __shfl_xor(dacc2, off);
        sacc0 += __shfl_xor(sacc0, off);
        sacc1 += __shfl_xor(sacc1, off);
        sacc2 += __shfl_xor(sacc2, off);
    }

    if (sub == 0) {
        const float ax = albedo[pix * 3 + 0];
        const float ay = albedo[pix * 3 + 1];
        const float az = albedo[pix * 3 + 2];
        const float inv_s = 1.0f / 64.0f;
        out[pix * 3 + 0] = (dacc0 * ax * 2.0f + sacc0) * inv_s;
        out[pix * 3 + 1] = (dacc1 * ay * 2.0f + sacc1) * inv_s;
        out[pix * 3 + 2] = (dacc2 * az * 2.0f + sacc2) * inv_s;
    }
}

extern "C" void kernel_launch(void* const* d_in, const int* in_sizes, int n_in,
                              void* d_out, int out_size, void* d_ws, size_t ws_size,
                              hipStream_t stream) {
    const float* normal    = (const float*)d_in[0];
    const float* albedo    = (const float*)d_in[1];
    const float* roughness = (const float*)d_in[2];
    const float* points    = (const float*)d_in[3];
    const float* cam       = (const float*)d_in[4];
    const float* ldir      = (const float*)d_in[5];
    const float* dlight    = (const float*)d_in[6];
    const float* hdir      = (const float*)d_in[7];
    const float* slight    = (const float*)d_in[8];
    float* out = (float*)d_out;

    // 16 lanes per pixel -> 16 pixels per 256-thread block
    const int blocks = N_PIX / 16;  // 8192
    shade_kernel<<<blocks, 256, 0, stream>>>(normal, albedo, roughness, points,
                                             cam, ldir, dlight, hdir, slight, out);
}